// Round 4
// baseline (219.352 us; speedup 1.0000x reference)
//
#include <hip/hip_runtime.h>
#include <stdint.h>

typedef unsigned short u16;
typedef short s16x8 __attribute__((ext_vector_type(8)));
typedef unsigned short u16x8 __attribute__((ext_vector_type(8)));
typedef unsigned short u16x4 __attribute__((ext_vector_type(4)));
typedef float f32x4 __attribute__((ext_vector_type(4)));
typedef float f32x16 __attribute__((ext_vector_type(16)));
typedef unsigned int u32x2 __attribute__((ext_vector_type(2)));

#define EXP2F(x) exp2f(x)
#define QSCALE 0.18033688011112042f  // 0.125 * log2(e): scores in exp2 domain

__device__ __forceinline__ u16 f2b(float f) {
  union { float f; uint32_t u; } v; v.f = f;
  uint32_t r = (v.u + 0x7fffu + ((v.u >> 16) & 1u)) >> 16;
  return (u16)r;
}

// pack high halves of two f32 bit patterns: result = hi16(lo) | hi16(hi)<<16
__device__ __forceinline__ uint32_t pkhi(uint32_t hi, uint32_t lo) {
#if __has_builtin(__builtin_amdgcn_perm)
  return __builtin_amdgcn_perm(hi, lo, 0x07060302u);
#else
  return (lo >> 16) | (hi & 0xffff0000u);
#endif
}

// CK-style barrier: waits LDS only, leaves global loads in flight (no vmcnt drain)
__device__ __forceinline__ void sync_lds() {
  asm volatile("s_waitcnt lgkmcnt(0)\ns_barrier" ::: "memory");
}

// ---------------------------------------------------------------------------
// fp32 -> bf16 cast, 8 elems/thread
// ---------------------------------------------------------------------------
__global__ __launch_bounds__(256)
void cast_bf16(const float* __restrict__ src, u16* __restrict__ dst) {
  const size_t i = ((size_t)blockIdx.x * 256 + threadIdx.x) * 8;
  f32x4 v0 = *(const f32x4*)(src + i);
  f32x4 v1 = *(const f32x4*)(src + i + 4);
  u16x8 u;
#pragma unroll
  for (int j = 0; j < 4; j++) { u[j] = f2b(v0[j]); u[4 + j] = f2b(v1[j]); }
  *(u16x8*)(dst + i) = u;
}

// ---------------------------------------------------------------------------
// Transpose + cast: src [K][N] fp32 -> dst [N][K] bf16
// ---------------------------------------------------------------------------
__global__ __launch_bounds__(256)
void transpose_cast(const float* __restrict__ src, u16* __restrict__ dst,
                    int K, int N) {
  __shared__ float tile[32][33];
  const int nb = blockIdx.x * 32, kb = blockIdx.y * 32;
  const int tx = threadIdx.x, ty = threadIdx.y;  // 32 x 8
#pragma unroll
  for (int i = 0; i < 4; i++)
    tile[ty + i * 8][tx] = src[(size_t)(kb + ty + i * 8) * N + nb + tx];
  __syncthreads();
#pragma unroll
  for (int i = 0; i < 4; i++)
    dst[(size_t)(nb + ty + i * 8) * K + kb + tx] = f2b(tile[tx][ty + i * 8]);
}

// ---------------------------------------------------------------------------
// GEMM: C[M,N] = A[M,K] * Bt[N,K]^T + bias[N]; A,Bt bf16.
// BK=64, XOR-swizzled LDS (slot = chunk ^ (row&7)), register-prefetch
// pipeline with CK barrier (global loads stay in flight across s_barrier).
// WN = column-waves (tile N = WN*64); 4 waves; tile M = 128.
// EPI 0 (WN=2): LDS-repack epilogue -> q (scaled), k [BH][N][D], v^T [BH][D][N]
// EPI 1: fp32 direct stores.
// ---------------------------------------------------------------------------
template <int EPI, int WN>
__global__ __launch_bounds__(256, 3)
void gemm_bt(const u16* __restrict__ A, const u16* __restrict__ Bt,
             const float* __restrict__ bias, float* __restrict__ outF,
             u16* __restrict__ outQ, u16* __restrict__ outK,
             u16* __restrict__ outVt, int M, int N, int K) {
  constexpr int BN = WN * 64;
  constexpr int RW = 4 / WN;         // row-wave groups
  constexpr int MI = 128 / RW / 16;  // 16-row tiles per wave
  constexpr int NBI = WN * 2;        // B staging b128 instrs per wave
  constexpr int SMEM = (EPI == 0) ? 34816 : (16384 + WN * 8192);
  __shared__ char smem[SMEM];
  u16* As = (u16*)smem;          // [128][64] swizzled
  u16* Bs = As + 128 * 64;       // [BN][64] swizzled

  const int t = threadIdx.x;
  const int m0 = blockIdx.y * 128, n0 = blockIdx.x * BN;
  const int w = t >> 6, lane = t & 63;
  const int wm = w / WN, wn = w % WN;
  const int quad = lane >> 4, lrow = lane & 15;
  const int r8 = lane >> 3, s8 = lane & 7;
  const int csw = (s8 ^ r8) * 8;  // swizzled source k-chunk (u16 units)

  const u16* gA = A + (size_t)(m0 + w * 32 + r8) * K + csw;
  const u16* gB = Bt + (size_t)(n0 + w * (WN * 16) + r8) * K + csw;
  u16* wAs = As + (w * 32 + r8) * 64 + s8 * 8;
  u16* wBs = Bs + (w * (WN * 16) + r8) * 64 + s8 * 8;

  f32x4 acc[MI][4];
#pragma unroll
  for (int i = 0; i < MI; i++)
#pragma unroll
    for (int j = 0; j < 4; j++) {
      f32x4 z = {0.f, 0.f, 0.f, 0.f};
      acc[i][j] = z;
    }

  u16x8 pa[4], pb[NBI];
#pragma unroll
  for (int i = 0; i < 4; i++) pa[i] = *(const u16x8*)(gA + (size_t)(i * 8) * K);
#pragma unroll
  for (int i = 0; i < NBI; i++) pb[i] = *(const u16x8*)(gB + (size_t)(i * 8) * K);

  const int KT = K >> 6;
  for (int kt = 0; kt < KT; ++kt) {
    sync_lds();  // prev iter's frag reads done (lgkm only)
#pragma unroll
    for (int i = 0; i < 4; i++) *(u16x8*)(wAs + i * 8 * 64) = pa[i];
#pragma unroll
    for (int i = 0; i < NBI; i++) *(u16x8*)(wBs + i * 8 * 64) = pb[i];
    if (kt + 1 < KT) {
      const size_t off = (size_t)(kt + 1) * 64;
#pragma unroll
      for (int i = 0; i < 4; i++)
        pa[i] = *(const u16x8*)(gA + (size_t)(i * 8) * K + off);
#pragma unroll
      for (int i = 0; i < NBI; i++)
        pb[i] = *(const u16x8*)(gB + (size_t)(i * 8) * K + off);
    }
    sync_lds();  // staged tile visible; prefetch loads remain in flight

#pragma unroll
    for (int ks = 0; ks < 2; ks++) {
      s16x8 a[MI], b[4];
#pragma unroll
      for (int i = 0; i < MI; i++)
        a[i] = *(const s16x8*)&As[(wm * (MI * 16) + i * 16 + lrow) * 64 +
                                  (((ks * 4 + quad) ^ (lrow & 7)) * 8)];
#pragma unroll
      for (int j = 0; j < 4; j++)
        b[j] = *(const s16x8*)&Bs[(wn * 64 + j * 16 + lrow) * 64 +
                                  (((ks * 4 + quad) ^ (lrow & 7)) * 8)];
#pragma unroll
      for (int i = 0; i < MI; i++)
#pragma unroll
        for (int j = 0; j < 4; j++)
          acc[i][j] = __builtin_amdgcn_mfma_f32_16x16x32_bf16(a[i], b[j],
                                                              acc[i][j], 0, 0, 0);
    }
  }

  if (EPI == 1) {
#pragma unroll
    for (int i = 0; i < MI; i++) {
      const int row = m0 + wm * (MI * 16) + i * 16 + quad * 4;
#pragma unroll
      for (int j = 0; j < 4; j++) {
        const int col = n0 + wn * 64 + j * 16 + lrow;
        const float bv = bias[col];
#pragma unroll
        for (int r = 0; r < 4; r++)
          outF[(size_t)(row + r) * N + col] = acc[i][j][r] + bv;
      }
    }
    return;
  }

  // EPI 0 (WN=2): per-wave 64x64 repack through LDS, coalesced 16B stores
  sync_lds();  // all frag reads of As/Bs done before overwrite
  u16* rp = (u16*)smem + w * (64 * 68);
  const int cb = n0 + wn * 64;  // wave's 64-col range = one (which,h)
  const int which = cb >> 10;   // 0=q 1=k 2=v
  const int h = (cb & 1023) >> 6;
  const int rbase = m0 + wm * 64;
  const int bb = rbase >> 11, nn0 = rbase & 2047;
  const int rl = lane >> 3, cc = (lane & 7) * 8;

  if (which != 2) {
    const float s = (which == 0) ? QSCALE : 1.0f;
#pragma unroll
    for (int i = 0; i < 4; i++)
#pragma unroll
      for (int j = 0; j < 4; j++) {
        const float bv = bias[cb + j * 16 + lrow];
#pragma unroll
        for (int r = 0; r < 4; r++)
          rp[(i * 16 + quad * 4 + r) * 68 + j * 16 + lrow] =
              f2b((acc[i][j][r] + bv) * s);
      }
    u16* dst = ((which == 0) ? outQ : outK) +
               ((size_t)(bb * 16 + h) * 2048 + nn0) * 64;
#pragma unroll
    for (int it = 0; it < 8; it++) {
      const int row = it * 8 + rl;
      *(u16x8*)&dst[(size_t)row * 64 + cc] = *(const u16x8*)&rp[row * 68 + cc];
    }
  } else {
#pragma unroll
    for (int i = 0; i < 4; i++)
#pragma unroll
      for (int j = 0; j < 4; j++) {
        const float bv = bias[cb + j * 16 + lrow];
        u16x4 pk;
#pragma unroll
        for (int r = 0; r < 4; r++) pk[r] = f2b(acc[i][j][r] + bv);
        *(u16x4*)&rp[(j * 16 + lrow) * 68 + i * 16 + quad * 4] = pk;
      }
    u16* dst = outVt + ((size_t)(bb * 16 + h) * 64) * 2048 + nn0;
#pragma unroll
    for (int it = 0; it < 8; it++) {
      const int d = it * 8 + rl;
      *(u16x8*)&dst[(size_t)d * 2048 + cc] = *(const u16x8*)&rp[d * 68 + cc];
    }
  }
}

// ---------------------------------------------------------------------------
// Flash attention, S^T on 32x32x16 MFMA, no-max exp2 softmax, register-
// prefetch K/V staging with CK barrier. Block = (bh, 64-q tile), 2 waves x
// 32 q. Q [BH][N][D] (pre-scaled, exp2 domain), K [BH][N][D], Vt [BH][D][N].
// XOR-swizzled Ks/Vs (slot = chunk ^ (row&7)). AO [B*N][C] bf16.
// 32x32 C/D: col=lane&31, row=(reg&3)+8*(reg>>2)+4*(lane>>5).
// ---------------------------------------------------------------------------
__global__ __launch_bounds__(128)
void attn_kernel(const u16* __restrict__ Q, const u16* __restrict__ Kg,
                 const u16* __restrict__ Vt, u16* __restrict__ AO) {
  __shared__ u16 Ks[64 * 64];     // [key][d] swizzled
  __shared__ u16 Vs[64 * 64];     // [d][key] swizzled
  __shared__ u16 Pt[2][32 * 72];  // per-wave [q][key]

  const int t = threadIdx.x;
  const int bh = blockIdx.x;  // 0..31; bh%8 fixes XCD -> per-head KV L2 reuse
  const int qt = blockIdx.y;  // 0..31
  const int w = t >> 6, lane = t & 63;
  const int l31 = lane & 31, lh = lane >> 5;
  const int r8 = lane >> 3, s8 = lane & 7;
  const int csw = (s8 ^ r8) * 8;
  const size_t base = (size_t)bh * 2048 * 64;

  // Q fragments (loaded once): B[n=q=l31][k = ks*16 + lh*8 + j]
  s16x8 qf[4];
  {
    const u16* qp = Q + base + (size_t)(qt * 64 + w * 32 + l31) * 64 + lh * 8;
#pragma unroll
    for (int ks = 0; ks < 4; ks++) qf[ks] = *(const s16x8*)(qp + ks * 16);
  }

  // staging: wave stages K rows [w*32,+32) and V d-rows [w*32,+32)
  const u16* gK = Kg + base + (size_t)(w * 32 + r8) * 64 + csw;
  const u16* gV = Vt + base + (size_t)(w * 32 + r8) * 2048 + csw;
  u16* wK = Ks + (w * 32 + r8) * 64 + s8 * 8;
  u16* wV = Vs + (w * 32 + r8) * 64 + s8 * 8;

  u16x8 pk_[4], pv_[4];
#pragma unroll
  for (int i = 0; i < 4; i++) {
    pk_[i] = *(const u16x8*)(gK + (size_t)(i * 8) * 64);
    pv_[i] = *(const u16x8*)(gV + (size_t)(i * 8) * 2048);
  }

  f32x16 ot0, ot1;
#pragma unroll
  for (int e = 0; e < 16; e++) { ot0[e] = 0.f; ot1[e] = 0.f; }
  float li = 0.f;

  for (int kt = 0; kt < 32; kt++) {
    sync_lds();
#pragma unroll
    for (int i = 0; i < 4; i++) {
      *(u16x8*)(wK + i * 8 * 64) = pk_[i];
      *(u16x8*)(wV + i * 8 * 64) = pv_[i];
    }
    if (kt + 1 < 32) {
      const u16* nK = gK + (size_t)(kt + 1) * 64 * 64;
      const u16* nV = gV + (kt + 1) * 64;
#pragma unroll
      for (int i = 0; i < 4; i++) {
        pk_[i] = *(const u16x8*)(nK + (size_t)(i * 8) * 64);
        pv_[i] = *(const u16x8*)(nV + (size_t)(i * 8) * 2048);
      }
    }
    sync_lds();

    // S^T = K . Q^T : key-tiles 0-31 / 32-63
    f32x16 sc0, sc1;
#pragma unroll
    for (int e = 0; e < 16; e++) { sc0[e] = 0.f; sc1[e] = 0.f; }
#pragma unroll
    for (int ks = 0; ks < 4; ks++) {
      const int sl = (((2 * ks + lh) ^ (l31 & 7)) * 8);
      s16x8 k0 = *(const s16x8*)&Ks[l31 * 64 + sl];
      s16x8 k1 = *(const s16x8*)&Ks[(32 + l31) * 64 + sl];
      sc0 = __builtin_amdgcn_mfma_f32_32x32x16_bf16(k0, qf[ks], sc0, 0, 0, 0);
      sc1 = __builtin_amdgcn_mfma_f32_32x32x16_bf16(k1, qf[ks], sc1, 0, 0, 0);
    }

    // exp2 softmax, no max-tracking; truncate to bf16; li from truncated p
    u16* prow = &Pt[w][l31 * 72];
    float rsum = 0.f;
#pragma unroll
    for (int tb = 0; tb < 2; tb++) {
      const f32x16& s = tb ? sc1 : sc0;
#pragma unroll
      for (int g = 0; g < 4; g++) {
        uint32_t u[4];
#pragma unroll
        for (int r = 0; r < 4; r++) {
          float p = EXP2F(s[g * 4 + r]);
          u[r] = __builtin_bit_cast(uint32_t, p);
          rsum += __builtin_bit_cast(float, u[r] & 0xffff0000u);
        }
        u32x2 pk;
        pk[0] = pkhi(u[1], u[0]);
        pk[1] = pkhi(u[3], u[2]);
        *(u32x2*)(prow + tb * 32 + g * 8 + lh * 4) = pk;
      }
    }
    li += rsum;

    // O^T += Vt . P^T : d-tiles 0-31 / 32-63 (Pt is wave-local, no barrier)
#pragma unroll
    for (int ks = 0; ks < 4; ks++) {
      const int sl = (((2 * ks + lh) ^ (l31 & 7)) * 8);
      s16x8 pf = *(const s16x8*)(prow + ks * 16 + lh * 8);
      s16x8 v0 = *(const s16x8*)&Vs[l31 * 64 + sl];
      s16x8 v1 = *(const s16x8*)&Vs[(32 + l31) * 64 + sl];
      ot0 = __builtin_amdgcn_mfma_f32_32x32x16_bf16(v0, pf, ot0, 0, 0, 0);
      ot1 = __builtin_amdgcn_mfma_f32_32x32x16_bf16(v1, pf, ot1, 0, 0, 0);
    }
  }

  // epilogue
  li += __shfl_xor(li, 32);
  const float inv = 1.0f / li;
  const int bb = bh >> 4, h = bh & 15;
  const int qn = qt * 64 + w * 32 + l31;
  u16* dst = AO + (size_t)(bb * 2048 + qn) * 1024 + h * 64;
#pragma unroll
  for (int db = 0; db < 2; db++) {
    const f32x16& o = db ? ot1 : ot0;
#pragma unroll
    for (int g = 0; g < 4; g++) {
      u16x4 pk;
#pragma unroll
      for (int r = 0; r < 4; r++) pk[r] = f2b(o[g * 4 + r] * inv);
      *(u16x4*)&dst[db * 32 + g * 8 + lh * 4] = pk;
    }
  }
}

// ---------------------------------------------------------------------------
extern "C" void kernel_launch(void* const* d_in, const int* in_sizes, int n_in,
                              void* d_out, int out_size, void* d_ws,
                              size_t ws_size, hipStream_t stream) {
  const float* x     = (const float*)d_in[0];  // [2,2048,1024]
  const float* w_qkv = (const float*)d_in[1];  // [1024,3072]
  const float* b_qkv = (const float*)d_in[2];  // [3072]
  const float* w_out = (const float*)d_in[3];  // [1024,1024]
  const float* b_out = (const float*)d_in[4];  // [1024]
  float* out = (float*)d_out;                  // [2,2048,1024]

  char* ws = (char*)d_ws;
  u16* wqT = (u16*)ws; ws += (size_t)3072 * 1024 * 2;
  u16* woT = (u16*)ws; ws += (size_t)1024 * 1024 * 2;
  u16* q   = (u16*)ws; ws += (size_t)32 * 2048 * 64 * 2;
  u16* k   = (u16*)ws; ws += (size_t)32 * 2048 * 64 * 2;
  u16* vt  = (u16*)ws; ws += (size_t)32 * 64 * 2048 * 2;
  u16* xb  = (u16*)ws; ws += (size_t)4096 * 1024 * 2;
  u16* ao  = xb;  // alias: xb dead after QKV GEMM, ao born in attention

  cast_bf16<<<dim3(2048), 256, 0, stream>>>(x, xb);
  transpose_cast<<<dim3(96, 32), dim3(32, 8), 0, stream>>>(w_qkv, wqT, 1024, 3072);
  transpose_cast<<<dim3(32, 32), dim3(32, 8), 0, stream>>>(w_out, woT, 1024, 1024);
  gemm_bt<0, 2><<<dim3(24, 32), 256, 0, stream>>>(xb, wqT, b_qkv, nullptr, q, k,
                                                  vt, 4096, 3072, 1024);
  attn_kernel<<<dim3(32, 32), 128, 0, stream>>>(q, k, vt, ao);
  gemm_bt<1, 1><<<dim3(16, 32), 256, 0, stream>>>(ao, woT, b_out, out, nullptr,
                                                  nullptr, nullptr, 4096, 1024, 1024);
}